// Round 11
// baseline (424.638 us; speedup 1.0000x reference)
//
#include <hip/hip_runtime.h>

#define SLEN 4096
#define DMODEL 768
#define NH 12
#define HD 64
#define NQKV 2304
#define KDIM 768
#define KVBLK 64
#define NT (SLEN / KVBLK)

typedef _Float16 f16x8 __attribute__((ext_vector_type(8)));
typedef _Float16 f16x4v __attribute__((ext_vector_type(4)));
typedef float f32x4 __attribute__((ext_vector_type(4)));
typedef float f32x16 __attribute__((ext_vector_type(16)));

__device__ __forceinline__ void async16(void* lds, const void* g) {
  __builtin_amdgcn_global_load_lds((const __attribute__((address_space(1))) void*)g,
                                   (__attribute__((address_space(3))) void*)lds, 16, 0, 0);
}

// permlane32_swap via builtin (SSA-safe; semantics HW-validated in R5)
__device__ __forceinline__ void plswap(unsigned& a, unsigned& b) {
  auto r = __builtin_amdgcn_permlane32_swap(a, b, false, false);
  a = r[0];
  b = r[1];
}

__device__ __forceinline__ unsigned pk(float a, float b) {
  auto r = __builtin_amdgcn_cvt_pkrtz(a, b);   // __fp16 ext_vector_type(2)
  return __builtin_bit_cast(unsigned, r);
}

// ---------------- pack / convert (vectorized) ----------------
__global__ __launch_bounds__(256) void pack_kernel(
    const float* __restrict__ x, const float* __restrict__ Wq, const float* __restrict__ Wk,
    const float* __restrict__ Wv, const float* __restrict__ Wo,
    _Float16* __restrict__ xb, _Float16* __restrict__ wqkvt, _Float16* __restrict__ wot) {
  int tid = blockIdx.x * 256 + threadIdx.x;
  int stride = gridDim.x * 256;
  int n4 = SLEN * DMODEL / 4;
  for (int i = tid; i < n4; i += stride) {
    float4 v = ((const float4*)x)[i];
    f16x4v o = {(_Float16)v.x, (_Float16)v.y, (_Float16)v.z, (_Float16)v.w};
    ((f16x4v*)xb)[i] = o;
  }
  // wqkvt[col][d], col = which*768 + h*64 + e
  n4 = NQKV * DMODEL / 4;
  for (int i = tid; i < n4; i += stride) {
    int col = i / (DMODEL / 4);
    int d = (i - col * (DMODEL / 4)) * 4;
    int which = col / DMODEL;
    int cc = col - which * DMODEL;
    int h = cc >> 6, e = cc & 63;
    const float* W = which == 0 ? Wq : (which == 1 ? Wk : Wv);
    const float* s = W + (h * DMODEL + d) * HD + e;
    f16x4v o = {(_Float16)s[0], (_Float16)s[HD], (_Float16)s[2 * HD], (_Float16)s[3 * HD]};
    ((f16x4v*)wqkvt)[i] = o;
  }
  // wot[o][d] = Wo[d*768+o]
  n4 = DMODEL * DMODEL / 4;
  for (int i = tid; i < n4; i += stride) {
    int o_ = i / (DMODEL / 4);
    int d = (i - o_ * (DMODEL / 4)) * 4;
    const float* s = Wo + d * DMODEL + o_;
    f16x4v o = {(_Float16)s[0], (_Float16)s[DMODEL], (_Float16)s[2 * DMODEL], (_Float16)s[3 * DMODEL]};
    ((f16x4v*)wot)[i] = o;
  }
}

// ---------------- QKV projection GEMM: 64x128 tiles, 1152 blocks (~4.5/CU) ----------------
__global__ __launch_bounds__(256, 5) void gemm_qkv(
    const _Float16* __restrict__ xb, const _Float16* __restrict__ wqkvt,
    const float* __restrict__ bq, const float* __restrict__ bk, const float* __restrict__ bv,
    _Float16* __restrict__ qd, _Float16* __restrict__ kd, _Float16* __restrict__ vtd) {
  __shared__ __align__(16) _Float16 As[64 * 64];    // 8 KB
  __shared__ __align__(16) _Float16 Bs[128 * 64];   // 16 KB
  int wg = blockIdx.x;
  int orig = (wg & 7) * 144 + (wg >> 3);  // bijective XCD swizzle (1152 = 8*144)
  int nb = orig % 18, mb = orig / 18;
  int m0 = mb * 64, n0 = nb * 128;
  int t = threadIdx.x, lane = t & 63, w = t >> 6;
  int lr = lane & 15, lg = lane >> 4;
  int wc = w;  // each wave owns a 64x32 output panel
  f32x4 acc[4][2] = {};
  for (int kb = 0; kb < KDIM / 64; ++kb) {
    #pragma unroll
    for (int i = 0; i < 2; ++i) {
      int base = (w * 2 + i) * 512;
      int off = base + lane * 8;
      int row = off >> 6, col = off & 63;
      async16(&As[base], xb + (m0 + row) * KDIM + kb * 64 + col);
    }
    #pragma unroll
    for (int i = 0; i < 4; ++i) {
      int base = (w * 4 + i) * 512;
      int off = base + lane * 8;
      int row = off >> 6, col = off & 63;
      async16(&Bs[base], wqkvt + (n0 + row) * KDIM + kb * 64 + col);
    }
    __syncthreads();
    #pragma unroll
    for (int kk = 0; kk < 2; ++kk) {
      f16x8 af[4], bf[2];
      #pragma unroll
      for (int mi = 0; mi < 4; ++mi)
        af[mi] = *(const f16x8*)&As[(mi * 16 + lr) * 64 + kk * 32 + lg * 8];
      #pragma unroll
      for (int ni = 0; ni < 2; ++ni)
        bf[ni] = *(const f16x8*)&Bs[(wc * 32 + ni * 16 + lr) * 64 + kk * 32 + lg * 8];
      #pragma unroll
      for (int mi = 0; mi < 4; ++mi)
        #pragma unroll
        for (int ni = 0; ni < 2; ++ni)
          acc[mi][ni] = __builtin_amdgcn_mfma_f32_16x16x32_f16(af[mi], bf[ni], acc[mi][ni], 0, 0, 0);
    }
    __syncthreads();
  }
  int which = n0 / DMODEL;  // 128-col block never straddles a 768 boundary
  const float* bias = which == 0 ? bq : (which == 1 ? bk : bv);
  #pragma unroll
  for (int mi = 0; mi < 4; ++mi)
    #pragma unroll
    for (int ni = 0; ni < 2; ++ni)
      #pragma unroll
      for (int r = 0; r < 4; ++r) {
        int srow = m0 + mi * 16 + lg * 4 + r;
        int col = n0 + wc * 32 + ni * 16 + lr;
        int cc = col - which * DMODEL;
        int h = cc >> 6, e = cc & 63;
        float val = acc[mi][ni][r] + bias[cc];
        if (which < 2) {
          (which ? kd : qd)[h * (SLEN * HD) + srow * HD + e] = (_Float16)val;
        } else {
          vtd[h * (SLEN * HD) + e * SLEN + srow] = (_Float16)val;  // V^T per head
        }
      }
}

// ---------------- flash attention: KV-split + 4 waves (2q x 2k); V global->reg; K LDS-dbuf ----------------
// LDS 16.5 KB -> 6 blocks/CU resident (24 waves/CU), single exact round at nsplit=2.
__global__ __launch_bounds__(256, 6) void attn_kernel(
    const _Float16* __restrict__ qd, const _Float16* __restrict__ kd,
    const _Float16* __restrict__ vtd, _Float16* __restrict__ Op, float* __restrict__ Ml,
    int nsplit, int tilesper) {
  __shared__ __align__(16) _Float16 Ks[2][KVBLK * HD];   // XOR-swizzled (16 KB)
  __shared__ float Mm[2][32], Lm[2][32];                 // merge scalars (512 B)
  int wg = blockIdx.x;
  int nwg = 768 * nsplit;
  int cpx = nwg >> 3;
  int orig = (wg & 7) * cpx + (wg >> 3);  // bijective XCD swizzle
  int s = orig % nsplit, u = orig / nsplit;
  int qb = u & 63, h = u >> 6;
  int t = threadIdx.x, lane = t & 63, w = t >> 6;
  int wq = w & 1, wk = w >> 1;
  int ql = lane & 31, hi = lane >> 5;

  const _Float16* kbase = kd + h * (SLEN * HD);
  const _Float16* vbase = vtd + h * (SLEN * HD);

  auto stage = [&](int bi, int jb) {
    #pragma unroll
    for (int i = 0; i < 2; ++i) {
      int c = (w * 2 + i) * 64 + lane;                   // 16B chunk id, 0..511
      int row = c >> 3;
      int sb = ((c & 7) * 16) ^ ((row & 7) << 4);        // inverse-swizzled source bytes
      async16(&Ks[bi][(w * 2 + i) * 512], kbase + (jb * KVBLK + row) * HD + sb / 2);
    }
  };

  int qrow = qb * 64 + wq * 32 + ql;
  const _Float16* qp = qd + h * (SLEN * HD) + qrow * HD;
  f16x8 qf[4];
  #pragma unroll
  for (int dblk = 0; dblk < 4; ++dblk)
    qf[dblk] = *(const f16x8*)(qp + dblk * 16 + hi * 8);

  f32x16 oacc[2] = {};
  float mrow = -1e30f, lrow = 0.f;
  const float C = 0.18033688f;   // (1/sqrt(64)) * log2(e)
  const float THR = 44.4f;       // defer-max threshold (p <= 2^8)

  int jb0 = s * tilesper;
  stage(0, jb0);
  __syncthreads();
  int buf = 0;
  for (int jj = 0; jj < tilesper; ++jj) {
    int jb = jb0 + jj;

    // V^T fragments: global -> regs, issued early (L2 latency hides under QK+softmax).
    // Identical logical elements to the old swizzled-LDS read.
    f16x8 vf[2][2];
    #pragma unroll
    for (int u2 = 0; u2 < 2; ++u2)
      #pragma unroll
      for (int eblk = 0; eblk < 2; ++eblk)
        vf[u2][eblk] = *(const f16x8*)(vbase + (eblk * 32 + ql) * SLEN + jb * KVBLK +
                                       wk * 32 + u2 * 16 + hi * 8);

    if (jj + 1 < tilesper) stage(buf ^ 1, jb + 1);  // 2-phase K prefetch

    // S^T[k][q] on this wave's 32-k slice
    f32x16 sacc = {};
    __builtin_amdgcn_s_setprio(1);
    #pragma unroll
    for (int dblk = 0; dblk < 4; ++dblk) {
      int off = ((wk * 32 + ql) * 128 + dblk * 32 + hi * 16) ^ ((ql & 7) << 4);
      f16x8 kf = *(const f16x8*)((const char*)Ks[buf] + off);
      sacc = __builtin_amdgcn_mfma_f32_32x32x16_f16(kf, qf[dblk], sacc, 0, 0, 0);
    }
    __builtin_amdgcn_s_setprio(0);

    // in-register online softmax
    float mb = sacc[0];
    #pragma unroll
    for (int r = 1; r < 16; ++r) mb = fmaxf(mb, sacc[r]);
    {
      unsigned a = __builtin_bit_cast(unsigned, mb), b = a;
      plswap(a, b);
      mb = fmaxf(__builtin_bit_cast(float, a), __builtin_bit_cast(float, b));
    }
    if (!__all(mb <= mrow + THR)) {  // T13 defer-max
      float mn = fmaxf(mrow, mb);
      float corr = __builtin_amdgcn_exp2f((mrow - mn) * C);
      lrow *= corr;
      #pragma unroll
      for (int r = 0; r < 16; ++r) { oacc[0][r] *= corr; oacc[1][r] *= corr; }
      mrow = mn;
    }
    float negm = -mrow * C;
    float p[16], ps = 0.f;
    #pragma unroll
    for (int r = 0; r < 16; ++r) { p[r] = __builtin_amdgcn_exp2f(fmaf(sacc[r], C, negm)); ps += p[r]; }
    lrow += ps;

    // pack P^T B-fragments (T12)
    f16x8 pb[2];
    #pragma unroll
    for (int u2 = 0; u2 < 2; ++u2) {
      unsigned a0 = pk(p[8 * u2 + 0], p[8 * u2 + 1]);
      unsigned b0 = pk(p[8 * u2 + 4], p[8 * u2 + 5]);
      unsigned a1 = pk(p[8 * u2 + 2], p[8 * u2 + 3]);
      unsigned b1 = pk(p[8 * u2 + 6], p[8 * u2 + 7]);
      plswap(a0, b0);
      plswap(a1, b1);
      union { unsigned wd[4]; f16x8 v; } uu;
      uu.wd[0] = a0; uu.wd[1] = a1; uu.wd[2] = b0; uu.wd[3] = b1;
      pb[u2] = uu.v;
    }

    // O^T += V^T * P^T (V from regs)
    __builtin_amdgcn_s_setprio(1);
    #pragma unroll
    for (int u2 = 0; u2 < 2; ++u2)
      #pragma unroll
      for (int eblk = 0; eblk < 2; ++eblk)
        oacc[eblk] = __builtin_amdgcn_mfma_f32_32x32x16_f16(vf[u2][eblk], pb[u2], oacc[eblk], 0, 0, 0);
    __builtin_amdgcn_s_setprio(0);
    __syncthreads();
    buf ^= 1;
  }

  // partner (hi-half) row-sum
  {
    unsigned a = __builtin_bit_cast(unsigned, lrow), b = a;
    plswap(a, b);
    lrow = __builtin_bit_cast(float, a) + __builtin_bit_cast(float, b);
  }

  // cross-wave (wk) flash merge; Om aliases the (dead) K staging buffers (16 KB exact)
  float* Om = (float*)&Ks[0][0];
  if (wk == 1) {
    Mm[wq][ql] = mrow;
    Lm[wq][ql] = lrow;
    #pragma unroll
    for (int eblk = 0; eblk < 2; ++eblk)
      #pragma unroll
      for (int r = 0; r < 16; ++r) {
        int e = eblk * 32 + (r & 3) + 8 * (r >> 2) + 4 * hi;
        Om[(wq * 64 + e) * 32 + ql] = oacc[eblk][r];
      }
  }
  __syncthreads();
  if (wk == 0) {
    float m1 = Mm[wq][ql], l1 = Lm[wq][ql];
    float m = fmaxf(mrow, m1);
    float c0 = __builtin_amdgcn_exp2f((mrow - m) * C);
    float c1 = __builtin_amdgcn_exp2f((m1 - m) * C);
    float ltot = lrow * c0 + l1 * c1;
    float inv = 1.f / ltot;
    int q = wq * 32 + ql;
    if (hi == 0) {
      Ml[orig * 128 + q] = m;
      Ml[orig * 128 + 64 + q] = ltot;
    }
    _Float16* ob = Op + (size_t)orig * 4096 + q * 64;  // [q][e], softmax-normalized
    #pragma unroll
    for (int eblk = 0; eblk < 2; ++eblk) {
      float om[16];
      #pragma unroll
      for (int r = 0; r < 16; ++r) {
        int e = eblk * 32 + (r & 3) + 8 * (r >> 2) + 4 * hi;
        om[r] = (oacc[eblk][r] * c0 + Om[(wq * 64 + e) * 32 + ql] * c1) * inv;
      }
      #pragma unroll
      for (int i = 0; i < 4; ++i) {
        unsigned w0 = pk(om[4 * i + 0], om[4 * i + 1]);
        unsigned w1 = pk(om[4 * i + 2], om[4 * i + 3]);
        union { unsigned wd[2]; f16x4v v; } uu;
        uu.wd[0] = w0; uu.wd[1] = w1;
        *(f16x4v*)(ob + eblk * 32 + 8 * i + 4 * hi) = uu.v;
      }
    }
  }
}

// ---------------- merge KV-split partials -> attn f16 buffer ----------------
__global__ __launch_bounds__(256) void merge_kernel(
    const _Float16* __restrict__ Op, const float* __restrict__ Ml,
    _Float16* __restrict__ attn, int nsplit) {
  const float C = 0.18033688f;
  int u = blockIdx.x;           // (h, qb) unit
  int qb = u & 63, h = u >> 6;
  int t = threadIdx.x;
  int e = t & 63, qg = t >> 6;
  for (int j = 0; j < 16; ++j) {
    int q = qg * 16 + j;
    float out;
    if (nsplit == 2) {
      int i0 = u * 2, i1 = u * 2 + 1;
      float m0 = Ml[i0 * 128 + q], l0 = Ml[i0 * 128 + 64 + q];
      float m1 = Ml[i1 * 128 + q], l1 = Ml[i1 * 128 + 64 + q];
      float m = fmaxf(m0, m1);
      float w0 = l0 * __builtin_amdgcn_exp2f((m0 - m) * C);
      float w1 = l1 * __builtin_amdgcn_exp2f((m1 - m) * C);
      float v0 = (float)Op[(size_t)i0 * 4096 + q * 64 + e];
      float v1 = (float)Op[(size_t)i1 * 4096 + q * 64 + e];
      out = (v0 * w0 + v1 * w1) / (w0 + w1);
    } else {
      out = (float)Op[(size_t)u * 4096 + q * 64 + e];
    }
    attn[(size_t)(qb * 64 + q) * DMODEL + h * HD + e] = (_Float16)out;
  }
}

// ---------------- output projection GEMM: 64x64 tiles, 768 blocks (3/CU) ----------------
__global__ __launch_bounds__(256) void gemm_out(
    const _Float16* __restrict__ attn, const _Float16* __restrict__ wot,
    const float* __restrict__ bo, float* __restrict__ out) {
  __shared__ __align__(16) _Float16 As[64 * 64];
  __shared__ __align__(16) _Float16 Bs[64 * 64];
  f32x4 acc[2][2] = {};
  int wg = blockIdx.x;
  int orig = (wg & 7) * 96 + (wg >> 3);  // bijective XCD swizzle (768 = 8*96)
  int mb = orig / 12, nb = orig - mb * 12;
  int m0 = mb * 64, n0 = nb * 64;
  int t = threadIdx.x, lane = t & 63, w = t >> 6;
  int lr = lane & 15, lg = lane >> 4;
  int wr = w >> 1, wc = w & 1;
  for (int kb = 0; kb < KDIM / 64; ++kb) {
    #pragma unroll
    for (int i = 0; i < 2; ++i) {
      int base = (w * 2 + i) * 512;
      int off = base + lane * 8;
      int row = off >> 6, col = off & 63;
      async16(&As[base], attn + (m0 + row) * DMODEL + kb * 64 + col);
      async16(&Bs[base], wot + (n0 + row) * DMODEL + kb * 64 + col);
    }
    __syncthreads();
    #pragma unroll
    for (int kk = 0; kk < 2; ++kk) {
      f16x8 af[2], bf[2];
      #pragma unroll
      for (int mi = 0; mi < 2; ++mi)
        af[mi] = *(const f16x8*)&As[(wr * 32 + mi * 16 + lr) * 64 + kk * 32 + lg * 8];
      #pragma unroll
      for (int ni = 0; ni < 2; ++ni)
        bf[ni] = *(const f16x8*)&Bs[(wc * 32 + ni * 16 + lr) * 64 + kk * 32 + lg * 8];
      #pragma unroll
      for (int mi = 0; mi < 2; ++mi)
        #pragma unroll
        for (int ni = 0; ni < 2; ++ni)
          acc[mi][ni] = __builtin_amdgcn_mfma_f32_16x16x32_f16(af[mi], bf[ni], acc[mi][ni], 0, 0, 0);
    }
    __syncthreads();
  }
  #pragma unroll
  for (int mi = 0; mi < 2; ++mi)
    #pragma unroll
    for (int ni = 0; ni < 2; ++ni)
      #pragma unroll
      for (int r = 0; r < 4; ++r) {
        int srow = m0 + wr * 32 + mi * 16 + lg * 4 + r;
        int col = n0 + wc * 32 + ni * 16 + lr;
        out[srow * DMODEL + col] = acc[mi][ni][r] + bo[col];
      }
}

extern "C" void kernel_launch(void* const* d_in, const int* in_sizes, int n_in,
                              void* d_out, int out_size, void* d_ws, size_t ws_size,
                              hipStream_t stream) {
  const float* x  = (const float*)d_in[0];
  const float* Wq = (const float*)d_in[1];
  const float* Wk = (const float*)d_in[2];
  const float* Wv = (const float*)d_in[3];
  const float* bq = (const float*)d_in[4];
  const float* bk = (const float*)d_in[5];
  const float* bv = (const float*)d_in[6];
  const float* Wo = (const float*)d_in[7];
  const float* bo = (const float*)d_in[8];
  float* out = (float*)d_out;

  char* ws = (char*)d_ws;
  size_t off = 0;
  auto alloc = [&](size_t bytes) {
    char* p = ws + off;
    off += (bytes + 255) & ~size_t(255);
    return p;
  };
  _Float16* xb    = (_Float16*)alloc((size_t)SLEN * DMODEL * 2);
  _Float16* wqkvt = (_Float16*)alloc((size_t)NQKV * DMODEL * 2);
  _Float16* wot   = (_Float16*)alloc((size_t)DMODEL * DMODEL * 2);
  _Float16* qd    = (_Float16*)alloc((size_t)NH * SLEN * HD * 2);
  _Float16* kd    = (_Float16*)alloc((size_t)NH * SLEN * HD * 2);
  _Float16* vtd   = (_Float16*)alloc((size_t)NH * SLEN * HD * 2);
  _Float16* attn  = (_Float16*)alloc((size_t)SLEN * DMODEL * 2);

  // KV-split partial buffers: choose nsplit=2 if workspace permits
  size_t need2 = ((size_t)1536 * 4096 * 2 + 255 + (size_t)1536 * 128 * 4 + 255);
  int nsplit = (ws_size >= off + need2) ? 2 : 1;
  int nunits = 768 * nsplit;
  _Float16* Op = (_Float16*)alloc((size_t)nunits * 4096 * 2);
  float*    Mlb = (float*)alloc((size_t)nunits * 128 * 4);

  hipLaunchKernelGGL(pack_kernel, dim3(1024), dim3(256), 0, stream,
                     x, Wq, Wk, Wv, Wo, xb, wqkvt, wot);
  hipLaunchKernelGGL(gemm_qkv, dim3(1152), dim3(256), 0, stream,
                     xb, wqkvt, bq, bk, bv, qd, kd, vtd);
  hipLaunchKernelGGL(attn_kernel, dim3(nunits), dim3(256), 0, stream,
                     qd, kd, vtd, Op, Mlb, nsplit, NT / nsplit);
  hipLaunchKernelGGL(merge_kernel, dim3(768), dim3(256), 0, stream,
                     Op, Mlb, attn, nsplit);
  hipLaunchKernelGGL(gemm_out, dim3(768), dim3(256), 0, stream,
                     attn, wot, bo, out);
}